// Round 3
// baseline (96.748 us; speedup 1.0000x reference)
//
#include <hip/hip_runtime.h>
#include <hip/hip_bf16.h>

// out[i] = x_i @ Q @ x_i, x [1024,2048] fp32 binary, Q [2048,2048] fp32.
// Identity: x^T Q x == x^T Q^T x, so the MFMA B-operand (N x K layout) is
// row-major Q directly — no transpose.
// Round 3: SINGLE fused kernel. fp32->bf16 conversion happens in the staging
// path (global_load -> v_cvt_pk_bf16 -> swizzled ds_write_b128), removing the
// prep kernel + 36 MB ws round-trip + inter-kernel gap. Register staging also
// lets us issue iter k+1's global loads BEFORE iter k's MFMAs (true pipelining
// that global_load_lds's barrier-drain cannot express).

#define B_ROWS 1024
#define N_BITS 2048

#define BM 128
#define BN 128
#define BK 64
#define KSPLIT 8
#define KPER (N_BITS / KSPLIT)   // 256
#define KITERS (KPER / BK)       // 4

typedef __bf16 bf16_t;
typedef __bf16 bf16x8 __attribute__((ext_vector_type(8)));
typedef float f32x4 __attribute__((ext_vector_type(4)));

// __launch_bounds__(256,3): ~170 VGPR budget (acc 64 + 64 pipeline staging +
// frags 40) -> 3 waves/SIMD, 3 blocks/CU (LDS 32KB allows 5).
__global__ __launch_bounds__(256, 3) void qubo_fused(
    const float* __restrict__ X, const float* __restrict__ Qm,
    float* __restrict__ out) {
  __shared__ bf16_t ldsA[BM * BK];   // 16 KB
  __shared__ bf16_t ldsB[BN * BK];   // 16 KB

  const int tid  = threadIdx.x;
  const int lane = tid & 63;
  const int wave = tid >> 6;     // 0..3 -> owns rows [wave*32, wave*32+32)
  const int lrow = lane & 15;
  const int quad = lane >> 4;

  const int m0    = blockIdx.y * BM;
  const int n0    = blockIdx.x * BN;
  const int kbase = blockIdx.z * KPER;

  // Staging decomposition: one chunk = 8 bf16 (32 B of fp32 in global, 16 B in
  // LDS). Per tile: 128 rows x 8 slots = 1024 chunks = 256 threads x 4 chunks.
  const int srow = tid >> 3;   // 0..31 (rows covered in 4 passes of 32)
  const int slot = tid & 7;    // chunk slot within a 64-elem row
  // XOR swizzle: global chunk g of row r lands in LDS slot g ^ (r&7) ->
  // frag ds_read_b128 later covers all 32 banks uniformly (conflict-free).
  const int swz = (slot ^ (srow & 7)) * 8;  // lds col (elems) for this thread

  const float* aSrc = X  + (size_t)(m0 + srow) * N_BITS + slot * 8;
  const float* bSrc = Qm + (size_t)(n0 + srow) * N_BITS + slot * 8;

  f32x4 acc[2][8];
#pragma unroll
  for (int i = 0; i < 2; ++i)
#pragma unroll
    for (int j = 0; j < 8; ++j) acc[i][j] = (f32x4){0.f, 0.f, 0.f, 0.f};

  // pipeline registers: 4 A-chunks + 4 B-chunks, 8 floats each
  float4 rA[4][2], rB[4][2];

#define LOAD_ITER(kt)                                                        \
  {                                                                          \
    const int k0 = kbase + (kt) * BK;                                        \
    _Pragma("unroll")                                                        \
    for (int p = 0; p < 4; ++p) {                                            \
      const float4* ga = (const float4*)(aSrc + (size_t)p * 32 * N_BITS + k0); \
      rA[p][0] = ga[0]; rA[p][1] = ga[1];                                    \
      const float4* gb = (const float4*)(bSrc + (size_t)p * 32 * N_BITS + k0); \
      rB[p][0] = gb[0]; rB[p][1] = gb[1];                                    \
    }                                                                        \
  }

  // convert 8 fp32 -> 8 bf16 and write 16B to LDS
#define CVT_STORE(dstBase, r0, r1)                                           \
  {                                                                          \
    union { int4 i4; __hip_bfloat162 h2[4]; } u;                             \
    u.h2[0] = __float22bfloat162_rn(make_float2((r0).x, (r0).y));            \
    u.h2[1] = __float22bfloat162_rn(make_float2((r0).z, (r0).w));            \
    u.h2[2] = __float22bfloat162_rn(make_float2((r1).x, (r1).y));            \
    u.h2[3] = __float22bfloat162_rn(make_float2((r1).z, (r1).w));            \
    *(int4*)(dstBase) = u.i4;                                                \
  }

  LOAD_ITER(0);

  for (int kt = 0; kt < KITERS; ++kt) {
    // drain this iter's staged registers into LDS
#pragma unroll
    for (int p = 0; p < 4; ++p) {
      const int r = p * 32 + srow;
      CVT_STORE(ldsA + r * BK + swz, rA[p][0], rA[p][1]);
      CVT_STORE(ldsB + r * BK + swz, rB[p][0], rB[p][1]);
    }
    __syncthreads();

    // issue next iter's global loads NOW — they overlap the MFMA section
    if (kt + 1 < KITERS) LOAD_ITER(kt + 1);

    const int sw = lrow & 7;
#pragma unroll
    for (int ks = 0; ks < 2; ++ks) {
      const int ch = ((ks * 4 + quad) ^ sw) * 8;  // swizzled chunk offset
      bf16x8 a[2], b[8];
#pragma unroll
      for (int mi = 0; mi < 2; ++mi)
        a[mi] = *(const bf16x8*)&ldsA[(wave * 32 + mi * 16 + lrow) * BK + ch];
#pragma unroll
      for (int ni = 0; ni < 8; ++ni)
        b[ni] = *(const bf16x8*)&ldsB[(ni * 16 + lrow) * BK + ch];
#pragma unroll
      for (int mi = 0; mi < 2; ++mi)
#pragma unroll
        for (int ni = 0; ni < 8; ++ni)
          acc[mi][ni] = __builtin_amdgcn_mfma_f32_16x16x32_bf16(
              a[mi], b[ni], acc[mi][ni], 0, 0, 0);
    }
    __syncthreads();
  }

  // Epilogue: out[row] += sum_col S[row,col] * x[row,col] over this block's
  // n-slice. C/D layout: col = lane&15, row = quad*4 + reg. Each row is owned
  // by exactly one wave -> one atomic per row per block.
#pragma unroll
  for (int mi = 0; mi < 2; ++mi) {
#pragma unroll
    for (int r = 0; r < 4; ++r) {
      const int row = m0 + wave * 32 + mi * 16 + quad * 4 + r;
      float s = 0.f;
#pragma unroll
      for (int ni = 0; ni < 8; ++ni) {
        const int col = n0 + ni * 16 + lrow;
        s += acc[mi][ni][r] * X[(size_t)row * N_BITS + col];
      }
#pragma unroll
      for (int off = 1; off < 16; off <<= 1)
        s += __shfl_xor(s, off, 64);
      if (lrow == 0) atomicAdd(&out[row], s);
    }
  }
}

extern "C" void kernel_launch(void* const* d_in, const int* in_sizes, int n_in,
                              void* d_out, int out_size, void* d_ws, size_t ws_size,
                              hipStream_t stream) {
  const float* x = (const float*)d_in[0];
  const float* Q = (const float*)d_in[1];
  float* out = (float*)d_out;

  // zero the atomic accumulation target (capture-safe: memset node on stream)
  hipMemsetAsync(out, 0, B_ROWS * sizeof(float), stream);

  dim3 grid(N_BITS / BN, B_ROWS / BM, KSPLIT);  // (16, 8, 8) = 1024 blocks
  qubo_fused<<<grid, dim3(256), 0, stream>>>(x, Q, out);
}